// Round 14
// baseline (1009.731 us; speedup 1.0000x reference)
//
#include <hip/hip_runtime.h>

#define N_NODES 100000
#define N_EDGES 1600000
#define E_TOT   1700000   // edges + self loops
#define HEADS   8
#define CH      32
#define F       256       // HEADS*CH
#define NCHUNK  ((N_NODES + 255) / 256)   // 391
#define EBLK    ((N_EDGES + 255) / 256)   // 6250: one edge per thread

static __device__ __forceinline__ float lrelu(float v, float s) { return fmaxf(v, s * v); }

static __device__ __forceinline__ unsigned short f2bf(float f) {
    unsigned u = __float_as_uint(f);
    u += 0x7FFFu + ((u >> 16) & 1u);      // round-to-nearest-even
    return (unsigned short)(u >> 16);
}
static __device__ __forceinline__ float bf2f(unsigned short u) {
    return __uint_as_float(((unsigned)u) << 16);
}

// 8-lane sum via DPP (VALU-only; validated r6/r10)
static __device__ __forceinline__ float dpp_sum8(float s) {
    s += __uint_as_float(__builtin_amdgcn_mov_dpp(__float_as_uint(s), 0xB1, 0xF, 0xF, true));  // quad_perm [1,0,3,2]
    s += __uint_as_float(__builtin_amdgcn_mov_dpp(__float_as_uint(s), 0x4E, 0xF, 0xF, true));  // quad_perm [2,3,0,1]
    s += __uint_as_float(__builtin_amdgcn_mov_dpp(__float_as_uint(s), 0x141, 0xF, 0xF, true)); // row_half_mirror
    return s;
}

// ======================= CSR build (once per call) =======================
__global__ __launch_bounds__(256) void k_deg_init(int* __restrict__ cnt, float* __restrict__ stats) {
    const int i = blockIdx.x * 256 + threadIdx.x;
    if (i < N_NODES) cnt[i] = 1;          // self loop
    if (blockIdx.x == 0 && threadIdx.x < 192) stats[threadIdx.x] = 0.f;
}

// one edge per thread: max wave-parallelism for latency-bound atomics (r12 win)
__global__ __launch_bounds__(256) void k_hist(const int* __restrict__ ei, int* __restrict__ cnt) {
    const int e = blockIdx.x * 256 + threadIdx.x;
    if (e < N_EDGES) atomicAdd(&cnt[ei[N_EDGES + e]], 1);
}

__global__ __launch_bounds__(256) void k_scan_chunk(
    const int* __restrict__ cnt, int* __restrict__ row_start, int* __restrict__ csum)
{
    __shared__ int s[256];
    const int t = threadIdx.x;
    const int i = blockIdx.x * 256 + t;
    const int v = (i < N_NODES) ? cnt[i] : 0;
    s[t] = v;
    __syncthreads();
    for (int off = 1; off < 256; off <<= 1) {
        const int y = (t >= off) ? s[t - off] : 0;
        __syncthreads();
        s[t] += y;
        __syncthreads();
    }
    if (i < N_NODES) row_start[i] = s[t] - v;   // exclusive
    if (t == 255) csum[blockIdx.x] = s[t];
}

__global__ __launch_bounds__(512) void k_scan_top(int* __restrict__ csum) {
    __shared__ int s[512];
    const int t = threadIdx.x;
    const int v = (t < NCHUNK) ? csum[t] : 0;
    s[t] = v;
    __syncthreads();
    for (int off = 1; off < 512; off <<= 1) {
        const int y = (t >= off) ? s[t - off] : 0;
        __syncthreads();
        s[t] += y;
        __syncthreads();
    }
    if (t < NCHUNK) csum[t] = s[t] - v;         // exclusive
}

__global__ __launch_bounds__(256) void k_fill_init(
    int* __restrict__ row_start, const int* __restrict__ csum,
    int* __restrict__ cursor, int* __restrict__ csr_src)
{
    const int i = blockIdx.x * 256 + threadIdx.x;
    if (i >= N_NODES) return;
    const int rs = row_start[i] + csum[i >> 8];
    row_start[i] = rs;
    cursor[i] = rs + 1;
    csr_src[rs] = i * 64;                       // self loop first (pre-scaled: ushort4-element offset)
}

// one edge per thread (r12 win)
__global__ __launch_bounds__(256) void k_fill(
    const int* __restrict__ ei, int* __restrict__ cursor, int* __restrict__ csr_src)
{
    const int e = blockIdx.x * 256 + threadIdx.x;
    if (e < N_EDGES) {
        const int pos = atomicAdd(&cursor[ei[N_EDGES + e]], 1);
        csr_src[pos] = ei[e] * 64;              // pre-scaled
    }
}
// after k_fill: cursor[i] == row_end[i]

// ====== xl = bn?(x) @ Wl (bf16), xr = bn?(x) @ Wr (bf16)  ([N,32]@[32,256]) ======
// NO LDS: x-row reads are wave-uniform -> scalar loads (SMEM), FMA with SGPR src.
// BN folded into weights: wl'[k] = psc_k*wl[k], acc init = sum_k psh_k*wl[k].
template <bool NORM>
__global__ __launch_bounds__(256) void k_gemm(
    const float* __restrict__ xin, const float* __restrict__ pstats,
    const float* __restrict__ pg, const float* __restrict__ pbe,
    const float* __restrict__ Wl, const float* __restrict__ Wr,
    unsigned short* __restrict__ xl, unsigned short* __restrict__ xr)
{
    const int t = threadIdx.x;
    float wl[CH], wr[CH];
    float bl = 0.f, br = 0.f;                   // BN shift folded through W
#pragma unroll
    for (int k = 0; k < CH; ++k) {
        float wkl = Wl[k * F + t];              // column t, coalesced
        float wkr = Wr[k * F + t];
        if (NORM) {
            const float mu  = pstats[k] * (1.f / N_NODES);       // uniform scalar loads
            const float var = pstats[32 + k] * (1.f / N_NODES) - mu * mu;
            const float sck = rsqrtf(var + 1e-5f) * pg[k];
            const float shk = pbe[k] - mu * sck;
            bl = fmaf(shk, wkl, bl);
            br = fmaf(shk, wkr, br);
            wkl *= sck;
            wkr *= sck;
        }
        wl[k] = wkl; wr[k] = wkr;
    }
    for (int r0 = blockIdx.x * 64; r0 < N_NODES; r0 += gridDim.x * 64) {
        const int rows = min(64, N_NODES - r0);
        for (int r = 0; r < rows; ++r) {
            const float* __restrict__ xrow = xin + (size_t)(r0 + r) * CH;  // wave-uniform
            float al0 = bl, ar0 = br, al1 = 0.f, ar1 = 0.f;
#pragma unroll
            for (int k = 0; k < CH; k += 2) {
                const float x0 = xrow[k];       // uniform -> s_load
                const float x1 = xrow[k + 1];
                al0 = fmaf(x0, wl[k], al0);
                ar0 = fmaf(x0, wr[k], ar0);
                al1 = fmaf(x1, wl[k + 1], al1);
                ar1 = fmaf(x1, wr[k + 1], ar1);
            }
            xl[(size_t)(r0 + r) * F + t] = f2bf(al0 + al1);
            xr[(size_t)(r0 + r) * F + t] = f2bf(ar0 + ar1);
        }
    }
}

// ============== single-pass GATv2 aggregation: one wave per dst node ==============
// lane l: head l>>3, channels 4*(l&7)..+3
// unroll-2, two chains, dpp reduce, gathers software-pipelined one iteration ahead (r11).
#define CHAIN(V, DEN, C0, C1, C2, C3)                                              \
    {                                                                              \
        const float x_ = bf2f(V.x), y_ = bf2f(V.y), z_ = bf2f(V.z), w_ = bf2f(V.w);\
        float s_ = lrelu(x_ + rx, 0.2f) * a4.x                                     \
                 + lrelu(y_ + ry, 0.2f) * a4.y                                     \
                 + lrelu(z_ + rz, 0.2f) * a4.z                                     \
                 + lrelu(w_ + rw, 0.2f) * a4.w;                                    \
        s_ = dpp_sum8(s_);                                                         \
        const float p_ = __expf(s_);                                               \
        DEN += p_;                                                                 \
        C0 = fmaf(p_, x_, C0);                                                     \
        C1 = fmaf(p_, y_, C1);                                                     \
        C2 = fmaf(p_, z_, C2);                                                     \
        C3 = fmaf(p_, w_, C3);                                                     \
    }

__global__ __launch_bounds__(256) void k_agg(
    const int* __restrict__ row_start, const int* __restrict__ row_end,
    const int* __restrict__ csr_src, const unsigned short* __restrict__ xl,
    const unsigned short* __restrict__ xr, const float* __restrict__ att,
    float* __restrict__ accum)
{
    const int lane = threadIdx.x & 63;
    const int wid  = (blockIdx.x * blockDim.x + threadIdx.x) >> 6;
    const int nw   = (gridDim.x * blockDim.x) >> 6;
    const float4 a4 = ((const float4*)att)[lane];
    const ushort4* __restrict__ xl4 = (const ushort4*)xl;
    for (int n = wid; n < N_NODES; n += nw) {
        const ushort4 vru = ((const ushort4*)(xr + (size_t)n * F))[lane];
        const float rx = bf2f(vru.x), ry = bf2f(vru.y), rz = bf2f(vru.z), rw = bf2f(vru.w);
        float c0a = 0.f, c1a = 0.f, c2a = 0.f, c3a = 0.f, dena = 0.f;
        float c0b = 0.f, c1b = 0.f, c2b = 0.f, c3b = 0.f, denb = 0.f;
        const int e0 = row_start[n], e1 = row_end[n];
        const int cnt   = e1 - e0;
        const int pairs = cnt >> 1;
        if (pairs > 0) {
            int e = e0;
            ushort4 va = xl4[(unsigned)csr_src[e]     + (unsigned)lane];
            ushort4 vb = xl4[(unsigned)csr_src[e + 1] + (unsigned)lane];
            e += 2;
            for (int p = 1; p < pairs; ++p, e += 2) {
                // issue NEXT pair's gathers before computing current pair
                const ushort4 vc = xl4[(unsigned)csr_src[e]     + (unsigned)lane];
                const ushort4 vd = xl4[(unsigned)csr_src[e + 1] + (unsigned)lane];
                CHAIN(va, dena, c0a, c1a, c2a, c3a)
                CHAIN(vb, denb, c0b, c1b, c2b, c3b)
                va = vc; vb = vd;
            }
            CHAIN(va, dena, c0a, c1a, c2a, c3a)
            CHAIN(vb, denb, c0b, c1b, c2b, c3b)
        }
        if (cnt & 1) {                             // remainder edge
            const ushort4 va = xl4[(unsigned)csr_src[e1 - 1] + (unsigned)lane];
            CHAIN(va, dena, c0a, c1a, c2a, c3a)
        }
        float c0 = c0a + c0b, c1 = c1a + c1b, c2 = c2a + c2b, c3 = c3a + c3b;
        const float inv = 0.125f / (dena + denb);  // alpha-normalize + head-mean
        c0 *= inv; c1 *= inv; c2 *= inv; c3 *= inv;
#pragma unroll
        for (int off = 8; off <= 32; off <<= 1) {  // sum the 8 heads
            c0 += __shfl_xor(c0, off);
            c1 += __shfl_xor(c1, off);
            c2 += __shfl_xor(c2, off);
            c3 += __shfl_xor(c3, off);
        }
        if (lane < 8)
            ((float4*)(accum + (size_t)n * CH))[lane] = make_float4(c0, c1, c2, c3);
    }
}

// ====== post: y = [lrelu](acc+bias) + residual(bn?(xprev)); batch stats ======
template <int MODE, bool NORM>   // MODE 0: leaky_relu 0.01 + residual, 1: residual only
__global__ __launch_bounds__(256) void k_post(
    float* __restrict__ y, const float* __restrict__ xprev,
    const float* __restrict__ pstats, const float* __restrict__ pg,
    const float* __restrict__ pbe, const float* __restrict__ bias,
    float* __restrict__ stats)
{
    __shared__ float s1[256], s2[256];
    const int t = threadIdx.x;
    const int c = t & 31;
    const float b = bias[c];
    float psc = 1.f, psh = 0.f;
    if (NORM) {
        const float mu  = pstats[c] * (1.f / N_NODES);
        const float var = pstats[32 + c] * (1.f / N_NODES) - mu * mu;
        psc = rsqrtf(var + 1e-5f) * pg[c];
        psh = pbe[c] - mu * psc;
    }
    float ls = 0.f, lq = 0.f;
    for (int i = blockIdx.x * 256 + t; i < N_NODES * CH; i += gridDim.x * 256) {
        float v = y[i] + b;
        if (MODE == 0) v = lrelu(v, 0.01f);
        const float xr_ = xprev[i];
        v += NORM ? fmaf(xr_, psc, psh) : xr_;
        y[i] = v;
        ls += v;
        lq = fmaf(v, v, lq);
    }
    s1[t] = ls; s2[t] = lq;
    __syncthreads();
    if (t < 32) {
        for (int j = 1; j < 8; ++j) { ls += s1[t + 32 * j]; lq += s2[t + 32 * j]; }
        atomicAdd(&stats[c], ls);
        atomicAdd(&stats[32 + c], lq);
    }
}

// ============== final batchnorm normalize → d_out ==============
__global__ __launch_bounds__(256) void k_bn(
    const float* __restrict__ y, const float* __restrict__ stats,
    const float* __restrict__ g, const float* __restrict__ be,
    float* __restrict__ xo)
{
    const int t = threadIdx.x;
    const int c = t & 31;
    const float mu  = stats[c] * (1.f / N_NODES);
    const float var = stats[32 + c] * (1.f / N_NODES) - mu * mu;
    const float sc  = rsqrtf(var + 1e-5f) * g[c];
    const float sh  = be[c] - mu * sc;
    for (int i = blockIdx.x * 256 + t; i < N_NODES * CH; i += gridDim.x * 256)
        xo[i] = fmaf(y[i], sc, sh);
}

extern "C" void kernel_launch(void* const* d_in, const int* in_sizes, int n_in,
                              void* d_out, int out_size, void* d_ws, size_t ws_size,
                              hipStream_t stream)
{
    const float* x0 = (const float*)d_in[0];
    const int*   ei = (const int*)d_in[1];

    char* ws = (char*)d_ws;
    unsigned short* xl    = (unsigned short*)ws;                          // N*256 bf16  51.2 MB
    unsigned short* xr    = xl + (size_t)N_NODES * F;                     // N*256 bf16  51.2 MB
    float*          accA  = (float*)(xr + (size_t)N_NODES * F);           // N*32  f32   12.8 MB
    float*          accB  = accA + (size_t)N_NODES * CH;                  // N*32  f32   12.8 MB
    float*          stats = accB + (size_t)N_NODES * CH;                  // 3*64
    int*            cnt   = (int*)(stats + 192);                          // N (cursor/row_end)
    int*            rowst = cnt + N_NODES;                                // N
    int*            csum  = rowst + N_NODES;                              // NCHUNK
    int*            csr   = csum + NCHUNK;                                // E_TOT  6.8 MB
    const size_t needed = (size_t)((char*)(csr + E_TOT) - ws);            // ~136 MB
    if (ws_size < needed) return;

    const float *Wl[3], *Wr[3], *att[3], *bb[3], *gg[3], *be[3];
    for (int L = 0; L < 3; ++L) {
        Wl[L]  = (const float*)d_in[3 + 6 * L + 0];
        Wr[L]  = (const float*)d_in[3 + 6 * L + 1];
        att[L] = (const float*)d_in[3 + 6 * L + 2];
        bb[L]  = (const float*)d_in[3 + 6 * L + 3];
        gg[L]  = (const float*)d_in[3 + 6 * L + 4];
        be[L]  = (const float*)d_in[3 + 6 * L + 5];
    }
    float* st0 = stats, *st1 = stats + 64, *st2 = stats + 128;

    // ---- CSR build (identical for all 3 layers) ----
    k_deg_init <<<NCHUNK, 256, 0, stream>>>(cnt, stats);
    k_hist     <<<EBLK,   256, 0, stream>>>(ei, cnt);
    k_scan_chunk<<<NCHUNK, 256, 0, stream>>>(cnt, rowst, csum);
    k_scan_top <<<1,      512, 0, stream>>>(csum);
    k_fill_init<<<NCHUNK, 256, 0, stream>>>(rowst, csum, cnt, csr);
    k_fill     <<<EBLK,   256, 0, stream>>>(ei, cnt, csr);

    // ---- layer 0: input x0 (raw) ----
    k_gemm<false><<<1563, 256, 0, stream>>>(x0, nullptr, nullptr, nullptr, Wl[0], Wr[0], xl, xr);
    k_agg        <<<2048, 256, 0, stream>>>(rowst, cnt, csr, xl, xr, att[0], accA);
    k_post<0, false><<<1024, 256, 0, stream>>>(accA, x0, nullptr, nullptr, nullptr, bb[0], st0);

    // ---- layer 1: input bn(accA; st0, g0, be0) ----
    k_gemm<true><<<1563, 256, 0, stream>>>(accA, st0, gg[0], be[0], Wl[1], Wr[1], xl, xr);
    k_agg       <<<2048, 256, 0, stream>>>(rowst, cnt, csr, xl, xr, att[1], accB);
    k_post<0, true><<<1024, 256, 0, stream>>>(accB, accA, st0, gg[0], be[0], bb[1], st1);

    // ---- layer 2: input bn(accB; st1, g1, be1) ----
    k_gemm<true><<<1563, 256, 0, stream>>>(accB, st1, gg[1], be[1], Wl[2], Wr[2], xl, xr);
    k_agg       <<<2048, 256, 0, stream>>>(rowst, cnt, csr, xl, xr, att[2], accA);
    k_post<1, true><<<1024, 256, 0, stream>>>(accA, accB, st1, gg[1], be[1], bb[2], st2);

    // ---- final BN -> d_out ----
    k_bn<<<2048, 256, 0, stream>>>(accA, st2, gg[2], be[2], (float*)d_out);

    (void)in_sizes; (void)n_in; (void)out_size;
}

// Round 15
// 787.407 us; speedup vs baseline: 1.2823x; 1.2823x over previous
//
#include <hip/hip_runtime.h>

#define N_NODES 100000
#define N_EDGES 1600000
#define E_TOT   1700000   // edges + self loops
#define HEADS   8
#define CH      32
#define F       256       // HEADS*CH
#define NCHUNK  ((N_NODES + 255) / 256)   // 391
#define EBLK    ((N_EDGES + 255) / 256)   // 6250: one edge per thread
#define TILES   (N_NODES / 16)            // 6250 exact row-tiles

typedef __attribute__((ext_vector_type(8))) short short8;   // 8 bf16 (4 VGPR)
typedef __attribute__((ext_vector_type(4))) float f32x4;    // MFMA acc

static __device__ __forceinline__ float lrelu(float v, float s) { return fmaxf(v, s * v); }

static __device__ __forceinline__ unsigned short f2bf(float f) {
    unsigned u = __float_as_uint(f);
    u += 0x7FFFu + ((u >> 16) & 1u);      // round-to-nearest-even
    return (unsigned short)(u >> 16);
}
static __device__ __forceinline__ float bf2f(unsigned short u) {
    return __uint_as_float(((unsigned)u) << 16);
}

// 8-lane sum via DPP (VALU-only; validated r6/r10)
static __device__ __forceinline__ float dpp_sum8(float s) {
    s += __uint_as_float(__builtin_amdgcn_mov_dpp(__float_as_uint(s), 0xB1, 0xF, 0xF, true));  // quad_perm [1,0,3,2]
    s += __uint_as_float(__builtin_amdgcn_mov_dpp(__float_as_uint(s), 0x4E, 0xF, 0xF, true));  // quad_perm [2,3,0,1]
    s += __uint_as_float(__builtin_amdgcn_mov_dpp(__float_as_uint(s), 0x141, 0xF, 0xF, true)); // row_half_mirror
    return s;
}

// ======================= CSR build (once per call) =======================
__global__ __launch_bounds__(256) void k_deg_init(int* __restrict__ cnt, float* __restrict__ stats) {
    const int i = blockIdx.x * 256 + threadIdx.x;
    if (i < N_NODES) cnt[i] = 1;          // self loop
    if (blockIdx.x == 0 && threadIdx.x < 192) stats[threadIdx.x] = 0.f;
}

// one edge per thread: max wave-parallelism for latency-bound atomics (r12 win)
__global__ __launch_bounds__(256) void k_hist(const int* __restrict__ ei, int* __restrict__ cnt) {
    const int e = blockIdx.x * 256 + threadIdx.x;
    if (e < N_EDGES) atomicAdd(&cnt[ei[N_EDGES + e]], 1);
}

__global__ __launch_bounds__(256) void k_scan_chunk(
    const int* __restrict__ cnt, int* __restrict__ row_start, int* __restrict__ csum)
{
    __shared__ int s[256];
    const int t = threadIdx.x;
    const int i = blockIdx.x * 256 + t;
    const int v = (i < N_NODES) ? cnt[i] : 0;
    s[t] = v;
    __syncthreads();
    for (int off = 1; off < 256; off <<= 1) {
        const int y = (t >= off) ? s[t - off] : 0;
        __syncthreads();
        s[t] += y;
        __syncthreads();
    }
    if (i < N_NODES) row_start[i] = s[t] - v;   // exclusive
    if (t == 255) csum[blockIdx.x] = s[t];
}

__global__ __launch_bounds__(512) void k_scan_top(int* __restrict__ csum) {
    __shared__ int s[512];
    const int t = threadIdx.x;
    const int v = (t < NCHUNK) ? csum[t] : 0;
    s[t] = v;
    __syncthreads();
    for (int off = 1; off < 512; off <<= 1) {
        const int y = (t >= off) ? s[t - off] : 0;
        __syncthreads();
        s[t] += y;
        __syncthreads();
    }
    if (t < NCHUNK) csum[t] = s[t] - v;         // exclusive
}

__global__ __launch_bounds__(256) void k_fill_init(
    int* __restrict__ row_start, const int* __restrict__ csum,
    int* __restrict__ cursor, int* __restrict__ csr_src)
{
    const int i = blockIdx.x * 256 + threadIdx.x;
    if (i >= N_NODES) return;
    const int rs = row_start[i] + csum[i >> 8];
    row_start[i] = rs;
    cursor[i] = rs + 1;
    csr_src[rs] = i * 64;                       // self loop first (pre-scaled: ushort4-element offset)
}

// one edge per thread (r12 win)
__global__ __launch_bounds__(256) void k_fill(
    const int* __restrict__ ei, int* __restrict__ cursor, int* __restrict__ csr_src)
{
    const int e = blockIdx.x * 256 + threadIdx.x;
    if (e < N_EDGES) {
        const int pos = atomicAdd(&cursor[ei[N_EDGES + e]], 1);
        csr_src[pos] = ei[e] * 64;              // pre-scaled
    }
}
// after k_fill: cursor[i] == row_end[i]

// ====== MFMA gemm: xl = bn?(x) @ Wl (bf16), xr = bn?(x) @ Wr (bf16) ======
// One wave per 16-row tile; K=32 in ONE mfma_f32_16x16x32_bf16.
// Lane l: m = l&15 (A-row / B-col / D-col), g = l>>4 (k-group: k = 8g..8g+7).
// D layout (m89-verified): col = lane&15, row = (lane>>4)*4 + reg.
// All 32 B-frags (16 col-blocks x {Wl,Wr}) held in registers for the whole kernel.
template <bool NORM>
__global__ __launch_bounds__(256) void k_gemm(
    const float* __restrict__ xin, const float* __restrict__ pstats,
    const float* __restrict__ pg, const float* __restrict__ pbe,
    const float* __restrict__ Wl, const float* __restrict__ Wr,
    unsigned short* __restrict__ xl, unsigned short* __restrict__ xr)
{
    const int lane = threadIdx.x & 63;
    const int m    = lane & 15;
    const int g    = lane >> 4;
    const int gwid = (blockIdx.x * blockDim.x + threadIdx.x) >> 6;
    const int nw   = (gridDim.x * blockDim.x) >> 6;

    // per-k BN coefficients for this lane's k-slice (k = 8g+j)
    float psc[8], psh[8];
    if (NORM) {
#pragma unroll
        for (int j = 0; j < 8; ++j) {
            const int k = 8 * g + j;
            const float mu  = pstats[k] * (1.f / N_NODES);
            const float var = pstats[32 + k] * (1.f / N_NODES) - mu * mu;
            psc[j] = rsqrtf(var + 1e-5f) * pg[k];
            psh[j] = pbe[k] - mu * psc[j];
        }
    }

    // B-frags: Wl/Wr [32 x 256] row-major; frag cb: B[k][cb*16+m], k=8g+j
    short8 BL[16], BR[16];
#pragma unroll
    for (int cb = 0; cb < 16; ++cb) {
        short8 bl, br;
#pragma unroll
        for (int j = 0; j < 8; ++j) {
            const int k = 8 * g + j;
            bl[j] = (short)f2bf(Wl[k * F + cb * 16 + m]);
            br[j] = (short)f2bf(Wr[k * F + cb * 16 + m]);
        }
        BL[cb] = bl; BR[cb] = br;
    }

    for (int tile = gwid; tile < TILES; tile += nw) {
        const int r0 = tile * 16;
        // A-frag: row r0+m, k-slice 8g..8g+7 (8 consecutive f32), BN inline
        const float* __restrict__ xrow = xin + (size_t)(r0 + m) * CH + 8 * g;
        short8 A;
#pragma unroll
        for (int j = 0; j < 8; ++j) {
            float v = xrow[j];
            if (NORM) v = fmaf(v, psc[j], psh[j]);
            A[j] = (short)f2bf(v);
        }
        unsigned short* __restrict__ outL = xl + (size_t)(r0 + 4 * g) * F + m;
        unsigned short* __restrict__ outR = xr + (size_t)(r0 + 4 * g) * F + m;
#pragma unroll
        for (int cb = 0; cb < 16; ++cb) {
            f32x4 accL = {0.f, 0.f, 0.f, 0.f};
            f32x4 accR = {0.f, 0.f, 0.f, 0.f};
            accL = __builtin_amdgcn_mfma_f32_16x16x32_bf16(A, BL[cb], accL, 0, 0, 0);
            accR = __builtin_amdgcn_mfma_f32_16x16x32_bf16(A, BR[cb], accR, 0, 0, 0);
            const int co = cb * 16;
            outL[co + 0 * F] = f2bf(accL[0]);
            outL[co + 1 * F] = f2bf(accL[1]);
            outL[co + 2 * F] = f2bf(accL[2]);
            outL[co + 3 * F] = f2bf(accL[3]);
            outR[co + 0 * F] = f2bf(accR[0]);
            outR[co + 1 * F] = f2bf(accR[1]);
            outR[co + 2 * F] = f2bf(accR[2]);
            outR[co + 3 * F] = f2bf(accR[3]);
        }
    }
}

// ============== single-pass GATv2 aggregation: one wave per dst node ==============
// lane l: head l>>3, channels 4*(l&7)..+3
// unroll-2, two chains, dpp reduce, gathers software-pipelined one iteration ahead (r11).
#define CHAIN(V, DEN, C0, C1, C2, C3)                                              \
    {                                                                              \
        const float x_ = bf2f(V.x), y_ = bf2f(V.y), z_ = bf2f(V.z), w_ = bf2f(V.w);\
        float s_ = lrelu(x_ + rx, 0.2f) * a4.x                                     \
                 + lrelu(y_ + ry, 0.2f) * a4.y                                     \
                 + lrelu(z_ + rz, 0.2f) * a4.z                                     \
                 + lrelu(w_ + rw, 0.2f) * a4.w;                                    \
        s_ = dpp_sum8(s_);                                                         \
        const float p_ = __expf(s_);                                               \
        DEN += p_;                                                                 \
        C0 = fmaf(p_, x_, C0);                                                     \
        C1 = fmaf(p_, y_, C1);                                                     \
        C2 = fmaf(p_, z_, C2);                                                     \
        C3 = fmaf(p_, w_, C3);                                                     \
    }

__global__ __launch_bounds__(256) void k_agg(
    const int* __restrict__ row_start, const int* __restrict__ row_end,
    const int* __restrict__ csr_src, const unsigned short* __restrict__ xl,
    const unsigned short* __restrict__ xr, const float* __restrict__ att,
    float* __restrict__ accum)
{
    const int lane = threadIdx.x & 63;
    const int wid  = (blockIdx.x * blockDim.x + threadIdx.x) >> 6;
    const int nw   = (gridDim.x * blockDim.x) >> 6;
    const float4 a4 = ((const float4*)att)[lane];
    const ushort4* __restrict__ xl4 = (const ushort4*)xl;
    for (int n = wid; n < N_NODES; n += nw) {
        const ushort4 vru = ((const ushort4*)(xr + (size_t)n * F))[lane];
        const float rx = bf2f(vru.x), ry = bf2f(vru.y), rz = bf2f(vru.z), rw = bf2f(vru.w);
        float c0a = 0.f, c1a = 0.f, c2a = 0.f, c3a = 0.f, dena = 0.f;
        float c0b = 0.f, c1b = 0.f, c2b = 0.f, c3b = 0.f, denb = 0.f;
        const int e0 = row_start[n], e1 = row_end[n];
        const int cnt   = e1 - e0;
        const int pairs = cnt >> 1;
        if (pairs > 0) {
            int e = e0;
            ushort4 va = xl4[(unsigned)csr_src[e]     + (unsigned)lane];
            ushort4 vb = xl4[(unsigned)csr_src[e + 1] + (unsigned)lane];
            e += 2;
            for (int p = 1; p < pairs; ++p, e += 2) {
                // issue NEXT pair's gathers before computing current pair
                const ushort4 vc = xl4[(unsigned)csr_src[e]     + (unsigned)lane];
                const ushort4 vd = xl4[(unsigned)csr_src[e + 1] + (unsigned)lane];
                CHAIN(va, dena, c0a, c1a, c2a, c3a)
                CHAIN(vb, denb, c0b, c1b, c2b, c3b)
                va = vc; vb = vd;
            }
            CHAIN(va, dena, c0a, c1a, c2a, c3a)
            CHAIN(vb, denb, c0b, c1b, c2b, c3b)
        }
        if (cnt & 1) {                             // remainder edge
            const ushort4 va = xl4[(unsigned)csr_src[e1 - 1] + (unsigned)lane];
            CHAIN(va, dena, c0a, c1a, c2a, c3a)
        }
        float c0 = c0a + c0b, c1 = c1a + c1b, c2 = c2a + c2b, c3 = c3a + c3b;
        const float inv = 0.125f / (dena + denb);  // alpha-normalize + head-mean
        c0 *= inv; c1 *= inv; c2 *= inv; c3 *= inv;
#pragma unroll
        for (int off = 8; off <= 32; off <<= 1) {  // sum the 8 heads
            c0 += __shfl_xor(c0, off);
            c1 += __shfl_xor(c1, off);
            c2 += __shfl_xor(c2, off);
            c3 += __shfl_xor(c3, off);
        }
        if (lane < 8)
            ((float4*)(accum + (size_t)n * CH))[lane] = make_float4(c0, c1, c2, c3);
    }
}

// ====== post: y = [lrelu](acc+bias) + residual(bn?(xprev)); batch stats ======
template <int MODE, bool NORM>   // MODE 0: leaky_relu 0.01 + residual, 1: residual only
__global__ __launch_bounds__(256) void k_post(
    float* __restrict__ y, const float* __restrict__ xprev,
    const float* __restrict__ pstats, const float* __restrict__ pg,
    const float* __restrict__ pbe, const float* __restrict__ bias,
    float* __restrict__ stats)
{
    __shared__ float s1[256], s2[256];
    const int t = threadIdx.x;
    const int c = t & 31;
    const float b = bias[c];
    float psc = 1.f, psh = 0.f;
    if (NORM) {
        const float mu  = pstats[c] * (1.f / N_NODES);
        const float var = pstats[32 + c] * (1.f / N_NODES) - mu * mu;
        psc = rsqrtf(var + 1e-5f) * pg[c];
        psh = pbe[c] - mu * psc;
    }
    float ls = 0.f, lq = 0.f;
    for (int i = blockIdx.x * 256 + t; i < N_NODES * CH; i += gridDim.x * 256) {
        float v = y[i] + b;
        if (MODE == 0) v = lrelu(v, 0.01f);
        const float xr_ = xprev[i];
        v += NORM ? fmaf(xr_, psc, psh) : xr_;
        y[i] = v;
        ls += v;
        lq = fmaf(v, v, lq);
    }
    s1[t] = ls; s2[t] = lq;
    __syncthreads();
    if (t < 32) {
        for (int j = 1; j < 8; ++j) { ls += s1[t + 32 * j]; lq += s2[t + 32 * j]; }
        atomicAdd(&stats[c], ls);
        atomicAdd(&stats[32 + c], lq);
    }
}

// ============== final batchnorm normalize → d_out ==============
__global__ __launch_bounds__(256) void k_bn(
    const float* __restrict__ y, const float* __restrict__ stats,
    const float* __restrict__ g, const float* __restrict__ be,
    float* __restrict__ xo)
{
    const int t = threadIdx.x;
    const int c = t & 31;
    const float mu  = stats[c] * (1.f / N_NODES);
    const float var = stats[32 + c] * (1.f / N_NODES) - mu * mu;
    const float sc  = rsqrtf(var + 1e-5f) * g[c];
    const float sh  = be[c] - mu * sc;
    for (int i = blockIdx.x * 256 + t; i < N_NODES * CH; i += gridDim.x * 256)
        xo[i] = fmaf(y[i], sc, sh);
}

extern "C" void kernel_launch(void* const* d_in, const int* in_sizes, int n_in,
                              void* d_out, int out_size, void* d_ws, size_t ws_size,
                              hipStream_t stream)
{
    const float* x0 = (const float*)d_in[0];
    const int*   ei = (const int*)d_in[1];

    char* ws = (char*)d_ws;
    unsigned short* xl    = (unsigned short*)ws;                          // N*256 bf16  51.2 MB
    unsigned short* xr    = xl + (size_t)N_NODES * F;                     // N*256 bf16  51.2 MB
    float*          accA  = (float*)(xr + (size_t)N_NODES * F);           // N*32  f32   12.8 MB
    float*          accB  = accA + (size_t)N_NODES * CH;                  // N*32  f32   12.8 MB
    float*          stats = accB + (size_t)N_NODES * CH;                  // 3*64
    int*            cnt   = (int*)(stats + 192);                          // N (cursor/row_end)
    int*            rowst = cnt + N_NODES;                                // N
    int*            csum  = rowst + N_NODES;                              // NCHUNK
    int*            csr   = csum + NCHUNK;                                // E_TOT  6.8 MB
    const size_t needed = (size_t)((char*)(csr + E_TOT) - ws);            // ~136 MB
    if (ws_size < needed) return;

    const float *Wl[3], *Wr[3], *att[3], *bb[3], *gg[3], *be[3];
    for (int L = 0; L < 3; ++L) {
        Wl[L]  = (const float*)d_in[3 + 6 * L + 0];
        Wr[L]  = (const float*)d_in[3 + 6 * L + 1];
        att[L] = (const float*)d_in[3 + 6 * L + 2];
        bb[L]  = (const float*)d_in[3 + 6 * L + 3];
        gg[L]  = (const float*)d_in[3 + 6 * L + 4];
        be[L]  = (const float*)d_in[3 + 6 * L + 5];
    }
    float* st0 = stats, *st1 = stats + 64, *st2 = stats + 128;

    // ---- CSR build (identical for all 3 layers) ----
    k_deg_init <<<NCHUNK, 256, 0, stream>>>(cnt, stats);
    k_hist     <<<EBLK,   256, 0, stream>>>(ei, cnt);
    k_scan_chunk<<<NCHUNK, 256, 0, stream>>>(cnt, rowst, csum);
    k_scan_top <<<1,      512, 0, stream>>>(csum);
    k_fill_init<<<NCHUNK, 256, 0, stream>>>(rowst, csum, cnt, csr);
    k_fill     <<<EBLK,   256, 0, stream>>>(ei, cnt, csr);

    // ---- layer 0: input x0 (raw) ----
    k_gemm<false><<<1563, 256, 0, stream>>>(x0, nullptr, nullptr, nullptr, Wl[0], Wr[0], xl, xr);
    k_agg        <<<2048, 256, 0, stream>>>(rowst, cnt, csr, xl, xr, att[0], accA);
    k_post<0, false><<<1024, 256, 0, stream>>>(accA, x0, nullptr, nullptr, nullptr, bb[0], st0);

    // ---- layer 1: input bn(accA; st0, g0, be0) ----
    k_gemm<true><<<1563, 256, 0, stream>>>(accA, st0, gg[0], be[0], Wl[1], Wr[1], xl, xr);
    k_agg       <<<2048, 256, 0, stream>>>(rowst, cnt, csr, xl, xr, att[1], accB);
    k_post<0, true><<<1024, 256, 0, stream>>>(accB, accA, st0, gg[0], be[0], bb[1], st1);

    // ---- layer 2: input bn(accB; st1, g1, be1) ----
    k_gemm<true><<<1563, 256, 0, stream>>>(accB, st1, gg[1], be[1], Wl[2], Wr[2], xl, xr);
    k_agg       <<<2048, 256, 0, stream>>>(rowst, cnt, csr, xl, xr, att[2], accA);
    k_post<1, true><<<1024, 256, 0, stream>>>(accA, accB, st1, gg[1], be[1], bb[2], st2);

    // ---- final BN -> d_out ----
    k_bn<<<2048, 256, 0, stream>>>(accA, st2, gg[2], be[2], (float*)d_out);

    (void)in_sizes; (void)n_in; (void)out_size;
}